// Round 13
// baseline (218.795 us; speedup 1.0000x reference)
//
#include <hip/hip_runtime.h>
#include <hip/hip_bf16.h>

typedef __attribute__((ext_vector_type(8))) unsigned short u16x8;
typedef __attribute__((ext_vector_type(8))) __bf16        bf16x8;
typedef __attribute__((ext_vector_type(4))) float         f32x4;

static constexpr int B_ = 8192;
static constexpr int I_ = 512;
static constexpr int H_ = 1024;
static constexpr int K_ = 1536;   // I_ + H_
static constexpr int NT = K_ / 64;   // 24 K-tiles of BK=64

#define AS1 __attribute__((address_space(1)))
#define AS3 __attribute__((address_space(3)))

__device__ __forceinline__ unsigned short f2bf(float f) {
    unsigned int u = __float_as_uint(f);
    u += 0x7FFF + ((u >> 16) & 1);          // RNE
    return (unsigned short)(u >> 16);
}
__device__ __forceinline__ float bf2f(unsigned short u) {
    return __uint_as_float(((unsigned int)u) << 16);
}

__device__ __forceinline__ void memfence() { asm volatile("" ::: "memory"); }
__device__ __forceinline__ void barrier_() {
    memfence(); __builtin_amdgcn_s_barrier(); memfence();
}
__device__ __forceinline__ void vwait8() {
    asm volatile("s_waitcnt vmcnt(8)" ::: "memory");
    __builtin_amdgcn_sched_barrier(0);
}
__device__ __forceinline__ void vwait12() {
    asm volatile("s_waitcnt vmcnt(12)" ::: "memory");
    __builtin_amdgcn_sched_barrier(0);
}
__device__ __forceinline__ void schedpin() { __builtin_amdgcn_sched_barrier(0); }

__device__ __forceinline__ u16x8 cvt8(const float4* s) {
    float4 a = s[0], b = s[1];
    u16x8 o;
    o[0] = f2bf(a.x); o[1] = f2bf(a.y); o[2] = f2bf(a.z); o[3] = f2bf(a.w);
    o[4] = f2bf(b.x); o[5] = f2bf(b.y); o[6] = f2bf(b.z); o[7] = f2bf(b.w);
    return o;
}

// ---- one-launch input prep: [x|hid]->cmb1 bf16, 3x W -> bf16 ---------------
__global__ void prep(const float* __restrict__ x, const float* __restrict__ hid,
                     const float* __restrict__ wt, const float* __restrict__ wr,
                     const float* __restrict__ wh,
                     unsigned short* __restrict__ cmb1,
                     unsigned short* __restrict__ wtb,
                     unsigned short* __restrict__ wrb,
                     unsigned short* __restrict__ whb) {
    constexpr int NX8 = B_ * I_ / 8;    // 524288
    constexpr int NH8 = B_ * H_ / 8;    // 1048576
    constexpr int NW8 = H_ * K_ / 8;    // 196608
    int i = blockIdx.x * blockDim.x + threadIdx.x;
    if (i < NX8) {
        int row = i >> 6, c8 = i & 63;
        u16x8 o = cvt8((const float4*)x + (size_t)i * 2);
        *(u16x8*)(cmb1 + (size_t)row * K_ + c8 * 8) = o;
    } else if (i < NX8 + NH8) {
        int j = i - NX8;
        int row = j >> 7, c8 = j & 127;
        u16x8 o = cvt8((const float4*)hid + (size_t)j * 2);
        *(u16x8*)(cmb1 + (size_t)row * K_ + 512 + c8 * 8) = o;
    } else {
        int k = i - (NX8 + NH8);
        const float* src; unsigned short* dst;
        if (k < NW8)          { src = wt; dst = wtb; }
        else if (k < 2 * NW8) { src = wr; dst = wrb; k -= NW8; }
        else                  { src = wh; dst = whb; k -= 2 * NW8; }
        u16x8 o = cvt8((const float4*)src + (size_t)k * 2);
        *(u16x8*)(dst + (size_t)k * 8) = o;
    }
}

// ===========================================================================
// gemmL<MODE>: A-in-LDS (dbuf), B DIRECT FROM GLOBAL (L2-resident W, 3 MB
// < 4 MB XCD L2) into double-buffered reg sets. BM=256, BN=128, waves 4x2,
// BK=64. Per tile: {readA(lo) 4 ds_reads + 16 MFMA; readA(hi) + 16 MFMA;
// vmcnt(8) [A(t+1) in LDS]; barrier; stageA(t+2) 4 gload_lds + loadB(t+2)
// 8 dwordx4; vmcnt(12) [B(t+1) regs ready]}. One barrier/tile. LDS carries
// only A: ~96 KB/tile vs 176 KB -> LDS-BW floor cut ~45%.
// Invariant at tile-t top: A(t) in buf t&1, B(t) in cur reg set, outstanding
// VMEM = [stageA(t+1) 4, loadB(t+1) 8]. Verified prologue/steady/tail.
//   MODE 0: itau_out[m*H_+n] = bf16(1/(softplus(z)+eps))
//   MODE 1: gate_out[m*K_+512+n] = bf16(sigmoid(z)*hidden_f32)
//   MODE 2: A k<512 from A1(cmb1), k>=512 from A2(cmb2:gated);
//           outF = h + (tanh(z)-h)*itau  (h f32, itau bf16)
// ===========================================================================
template<int MODE>
__global__ __launch_bounds__(512, 1)
void gemmL(const unsigned short* __restrict__ A1,
           const unsigned short* __restrict__ A2,
           const unsigned short* __restrict__ W0,
           const float* __restrict__ bias0,
           const float* __restrict__ hidden,
           const unsigned short* __restrict__ itau_in,
           float* __restrict__ outF,
           unsigned short* __restrict__ itau_out,
           unsigned short* __restrict__ gate_out)
{
    extern __shared__ __align__(16) char lds[];   // A only: 2 bufs x 32768

    const int t = threadIdx.x;
    const int w = t >> 6, l = t & 63;
    const int wg  = blockIdx.y * 8 + blockIdx.x;
    const int swz = (wg & 7) * 32 + (wg >> 3);   // XCD c <- 4 m-panels x 8 n
    const int m0  = (swz >> 3) * 256;
    const int n0  = (swz & 7) * 128;

    // ---- A staging (linear LDS dest, pre-swizzled source slot) ------------
    const int srow  = t >> 3;                       // 0..63
    const int sslot = ((t & 7) ^ (srow & 7)) * 8;
    const unsigned short* srcA1 = A1 + (size_t)(m0 + srow) * K_ + sslot;
    const unsigned short* srcA2 = A2 + (size_t)(m0 + srow) * K_ + sslot;
    char* dstA = lds + w * 1024;

    auto stageA = [&](int tt) {                     // full 256-row A tile
        const unsigned short* base = (MODE == 2 && tt >= 8) ? srcA2 : srcA1;
        const unsigned short* s = base + tt * 64;
        char* d = dstA + (tt & 1) * 32768;
        #pragma unroll
        for (int q = 0; q < 4; ++q)                 // rows q*64 + srow
            __builtin_amdgcn_global_load_lds(
                (const AS1 void*)(s + (size_t)q * 64 * K_),
                (AS3 void*)(d + q * 8192), 16, 0, 0);
    };

    // ---- fragment geometry ------------------------------------------------
    const int fr = l & 15, kq = l >> 4;
    const int wm = w >> 1, wn = w & 1;              // waves 4 x 2
    const int fx = (kq ^ (fr & 7)) << 4;
    const char* rdA0 = lds + (wm * 32 + fr) * 128 + fx;
    const char* rdA1 = lds + (wm * 32 + fr) * 128 + (fx ^ 64);

    // B direct-load base: lane row = n0 + wn*32 + fr, k-slot kq*8
    const unsigned short* baseB = W0 + (size_t)(n0 + wn * 32 + fr) * K_ + kq * 8;

    bf16x8 af[2][2];
    bf16x8 BA[2][2][2], BB[2][2][2];                // [bh][ni][ks]
    f32x4 acc[4][4];
    #pragma unroll
    for (int i = 0; i < 4; ++i)
        #pragma unroll
        for (int jn = 0; jn < 4; ++jn) acc[i][jn] = (f32x4)0.0f;

    auto readA = [&](int half, int par) {
        #pragma unroll
        for (int mi = 0; mi < 2; ++mi) {
            af[mi][0] = *(const bf16x8*)(rdA0 + par * 32768 + half * 16384 + mi * 2048);
            af[mi][1] = *(const bf16x8*)(rdA1 + par * 32768 + half * 16384 + mi * 2048);
        }
    };
    auto loadB = [&](bf16x8 (&Bq)[2][2][2], int tt) {   // 8 dwordx4 from L2
        const unsigned short* p = baseB + tt * 64;
        #pragma unroll
        for (int bh = 0; bh < 2; ++bh)
            #pragma unroll
            for (int ni = 0; ni < 2; ++ni)
                #pragma unroll
                for (int ks = 0; ks < 2; ++ks)
                    Bq[bh][ni][ks] = *(const bf16x8*)(p
                        + (size_t)(bh * 64 + ni * 16) * K_ + ks * 32);
    };
    auto quad16 = [&](const bf16x8 (&Bq)[2][2][2], int ah) {
        __builtin_amdgcn_s_setprio(1);
        #pragma unroll
        for (int bh = 0; bh < 2; ++bh)
            #pragma unroll
            for (int mi = 0; mi < 2; ++mi)
                #pragma unroll
                for (int ni = 0; ni < 2; ++ni)
                    #pragma unroll
                    for (int ks = 0; ks < 2; ++ks)
                        acc[ah * 2 + mi][bh * 2 + ni] =
                            __builtin_amdgcn_mfma_f32_16x16x32_bf16(
                                af[mi][ks], Bq[bh][ni][ks],
                                acc[ah * 2 + mi][bh * 2 + ni], 0, 0, 0);
        __builtin_amdgcn_s_setprio(0);
    };

    // ---- prologue: invariant = A(0),B(0) ready; outstanding [A(1),B(1)] ---
    stageA(0); schedpin(); loadB(BA, 0); schedpin();
    stageA(1); schedpin(); loadB(BB, 1); schedpin();
    vwait12(); barrier_();

    // ---- main loop: 12 iters x 2 tiles (even uses BA/buf0, odd BB/buf1) ---
    #define CLMP(X) (((X) < NT) ? (X) : 0)
    for (int j = 0; j < NT / 2; ++j) {
        const int te = 2 * j, to = 2 * j + 1;
        // tile even
        readA(0, 0); quad16(BA, 0);
        readA(1, 0); quad16(BA, 1);
        vwait8(); barrier_();
        stageA(CLMP(te + 2)); schedpin(); loadB(BA, CLMP(te + 2)); schedpin();
        vwait12();
        // tile odd
        readA(0, 1); quad16(BB, 0);
        readA(1, 1); quad16(BB, 1);
        vwait8(); barrier_();
        stageA(CLMP(to + 2)); schedpin(); loadB(BB, CLMP(to + 2)); schedpin();
        vwait12();
    }
    #undef CLMP
    asm volatile("s_waitcnt vmcnt(0)" ::: "memory");

    // ---- epilogue: C/D col = lane&15, row = (lane>>4)*4 + jj --------------
    const int rs4 = kq * 4;
    const int nB0 = n0 + wn * 32;
    const int mB0 = m0 + wm * 32;
    #pragma unroll
    for (int ah = 0; ah < 2; ++ah)
        #pragma unroll
        for (int mi = 0; mi < 2; ++mi)
            #pragma unroll
            for (int bh = 0; bh < 2; ++bh)
                #pragma unroll
                for (int ni = 0; ni < 2; ++ni) {
                    const int n = nB0 + bh * 64 + ni * 16 + fr;
                    const float bv = bias0[n];
                    #pragma unroll
                    for (int jj = 0; jj < 4; ++jj) {
                        const int m = mB0 + ah * 128 + mi * 16 + rs4 + jj;
                        const size_t ix = (size_t)m * H_ + n;
                        const float z = acc[ah * 2 + mi][bh * 2 + ni][jj] + bv;
                        if (MODE == 0) {
                            const float sp = (z > 15.f) ? z : __logf(1.0f + __expf(z));
                            itau_out[ix] = f2bf(__fdividef(1.0f, sp + 1e-6f));
                        } else if (MODE == 1) {
                            const float r = __fdividef(1.0f, 1.0f + __expf(-z));
                            gate_out[(size_t)m * K_ + 512 + n] = f2bf(r * hidden[ix]);
                        } else {
                            const float e2 = __expf(2.0f * z);
                            const float th = __fdividef(e2 - 1.0f, e2 + 1.0f);
                            const float h = hidden[ix];
                            const float it = bf2f(itau_in[ix]);
                            outF[ix] = h + (th - h) * it;
                        }
                    }
                }
}

extern "C" void kernel_launch(void* const* d_in, const int* in_sizes, int n_in,
                              void* d_out, int out_size, void* d_ws, size_t ws_size,
                              hipStream_t stream) {
    (void)in_sizes; (void)n_in; (void)out_size; (void)ws_size;

    const float* x     = (const float*)d_in[0];
    const float* hid   = (const float*)d_in[1];
    const float* W_tau = (const float*)d_in[2];
    const float* b_tau = (const float*)d_in[3];
    const float* W_r   = (const float*)d_in[4];
    const float* b_r   = (const float*)d_in[5];
    const float* W_h   = (const float*)d_in[6];
    const float* b_h   = (const float*)d_in[7];

    // workspace (~76.5 MB)
    unsigned short* cmb1 = (unsigned short*)d_ws;          // [8192][1536] = [x|hidden]
    unsigned short* cmb2 = cmb1 + (size_t)B_ * K_;         // [8192][1536] (gated in cols 512+)
    unsigned short* wtb  = cmb2 + (size_t)B_ * K_;         // [1024][1536]
    unsigned short* wrb  = wtb  + (size_t)H_ * K_;         // [1024][1536]
    unsigned short* whb  = wrb  + (size_t)H_ * K_;         // [1024][1536]
    unsigned short* itau = whb  + (size_t)H_ * K_;         // [8192][1024] bf16

    hipFuncSetAttribute(reinterpret_cast<const void*>(&gemmL<0>),
                        hipFuncAttributeMaxDynamicSharedMemorySize, 65536);
    hipFuncSetAttribute(reinterpret_cast<const void*>(&gemmL<1>),
                        hipFuncAttributeMaxDynamicSharedMemorySize, 65536);
    hipFuncSetAttribute(reinterpret_cast<const void*>(&gemmL<2>),
                        hipFuncAttributeMaxDynamicSharedMemorySize, 65536);

    const int th = 256;
    constexpr int NPREP = B_ * I_ / 8 + B_ * H_ / 8 + 3 * H_ * K_ / 8; // 2162688
    prep<<<NPREP / th, th, 0, stream>>>(x, hid, W_tau, W_r, W_h,
                                        cmb1, wtb, wrb, whb);

    dim3 g(8, 32);   // 256 blocks, 1/CU
    gemmL<0><<<g, 512, 65536, stream>>>(cmb1, cmb1, wtb, b_tau, hid, nullptr,
                                        nullptr, itau, nullptr);
    gemmL<1><<<g, 512, 65536, stream>>>(cmb1, cmb1, wrb, b_r, hid, nullptr,
                                        nullptr, nullptr, cmb2);
    gemmL<2><<<g, 512, 65536, stream>>>(cmb1, cmb2, whb, b_h, hid, itau,
                                        (float*)d_out, nullptr, nullptr);
}

// Round 14
// 112.864 us; speedup vs baseline: 1.9386x; 1.9386x over previous
//
#include <hip/hip_runtime.h>
#include <hip/hip_bf16.h>

typedef __attribute__((ext_vector_type(8))) unsigned short u16x8;
typedef __attribute__((ext_vector_type(8))) __bf16        bf16x8;
typedef __attribute__((ext_vector_type(4))) float         f32x4;

static constexpr int B_ = 8192;
static constexpr int I_ = 512;
static constexpr int H_ = 1024;
static constexpr int K_ = 1536;   // I_ + H_
static constexpr int NT    = K_ / 64;   // 24 K-tiles of BK=64
static constexpr int NITER = NT / 2;    // 12 iterations (2 tiles each)

#define AS1 __attribute__((address_space(1)))
#define AS3 __attribute__((address_space(3)))

__device__ __forceinline__ unsigned short f2bf(float f) {
    unsigned int u = __float_as_uint(f);
    u += 0x7FFF + ((u >> 16) & 1);          // RNE
    return (unsigned short)(u >> 16);
}
__device__ __forceinline__ float bf2f(unsigned short u) {
    return __uint_as_float(((unsigned int)u) << 16);
}

__device__ __forceinline__ void memfence() { asm volatile("" ::: "memory"); }
__device__ __forceinline__ void barrier_() {
    memfence(); __builtin_amdgcn_s_barrier(); memfence();
}
__device__ __forceinline__ void vwait4() {
    asm volatile("s_waitcnt vmcnt(4)" ::: "memory");
    __builtin_amdgcn_sched_barrier(0);
}

__device__ __forceinline__ u16x8 cvt8(const float4* s) {
    float4 a = s[0], b = s[1];
    u16x8 o;
    o[0] = f2bf(a.x); o[1] = f2bf(a.y); o[2] = f2bf(a.z); o[3] = f2bf(a.w);
    o[4] = f2bf(b.x); o[5] = f2bf(b.y); o[6] = f2bf(b.z); o[7] = f2bf(b.w);
    return o;
}

// ---- one-launch input prep: [x|hid]->cmb1 bf16, 3x W -> bf16 ---------------
__global__ void prep(const float* __restrict__ x, const float* __restrict__ hid,
                     const float* __restrict__ wt, const float* __restrict__ wr,
                     const float* __restrict__ wh,
                     unsigned short* __restrict__ cmb1,
                     unsigned short* __restrict__ wtb,
                     unsigned short* __restrict__ wrb,
                     unsigned short* __restrict__ whb) {
    constexpr int NX8 = B_ * I_ / 8;    // 524288
    constexpr int NH8 = B_ * H_ / 8;    // 1048576
    constexpr int NW8 = H_ * K_ / 8;    // 196608
    int i = blockIdx.x * blockDim.x + threadIdx.x;
    if (i < NX8) {
        int row = i >> 6, c8 = i & 63;
        u16x8 o = cvt8((const float4*)x + (size_t)i * 2);
        *(u16x8*)(cmb1 + (size_t)row * K_ + c8 * 8) = o;
    } else if (i < NX8 + NH8) {
        int j = i - NX8;
        int row = j >> 7, c8 = j & 127;
        u16x8 o = cvt8((const float4*)hid + (size_t)j * 2);
        *(u16x8*)(cmb1 + (size_t)row * K_ + 512 + c8 * 8) = o;
    } else {
        int k = i - (NX8 + NH8);
        const float* src; unsigned short* dst;
        if (k < NW8)          { src = wt; dst = wtb; }
        else if (k < 2 * NW8) { src = wr; dst = wrb; k -= NW8; }
        else                  { src = wh; dst = whb; k -= 2 * NW8; }
        u16x8 o = cvt8((const float4*)src + (size_t)k * 2);
        *(u16x8*)(dst + (size_t)k * 8) = o;
    }
}

// ===========================================================================
// gemm4<MODE>: R8/R12-proven 4-phase structure. BM=256, BN=128, waves 4x2,
// BK=64, 2 tiles/iter, 16-MFMA phases (A-half x B-full; 8 B-frags in regs).
// One barrier per phase; vmcnt(4) at P2/P4. Race-free stage-after-last-read:
//   P1: readA(lo,b0)+readBall(b0); stage A-hi(2j+1 -> b1)
//   P2: readA(hi,b0); stage A-lo+B(2j+2 -> b0); vmcnt(4)
//   P3: readA(lo,b1)+readBall(b1); stage A-hi(2j+2 -> b0)
//   P4: readA(hi,b1); stage A-lo+B(2j+3 -> b1); vmcnt(4)
// Epilogues use R8-proven COALESCED patterns: hidden as f32 (64B segments),
// itau as bf16. (R12's bf16-hidden scatter reads cost +12 us on mode 2.)
//   MODE 0: itau_out[m*H_+n] = bf16(1/(softplus(z)+eps))
//   MODE 1: gate_out[m*K_+512+n] = bf16(sigmoid(z) * hidden_f32)
//   MODE 2: A k<512 from A1(cmb1), k>=512 from A2(cmb2:gated);
//           outF = h + (tanh(z)-h)*itau   (h f32, itau bf16)
// ===========================================================================
template<int MODE>
__global__ __launch_bounds__(512, 1)
void gemm4(const unsigned short* __restrict__ A1,
           const unsigned short* __restrict__ A2,
           const unsigned short* __restrict__ W0,
           const float* __restrict__ bias0,
           const float* __restrict__ hidden,
           const unsigned short* __restrict__ itau_in,
           float* __restrict__ outF,
           unsigned short* __restrict__ itau_out,
           unsigned short* __restrict__ gate_out)
{
    extern __shared__ __align__(16) char lds[];
    // A: [0,65536) 2 bufs x 32768 ; B: [65536,98304) 2 bufs x 16384

    const int t = threadIdx.x;
    const int w = t >> 6, l = t & 63;
    const int wg  = blockIdx.y * 8 + blockIdx.x;
    const int swz = (wg & 7) * 32 + (wg >> 3);   // XCD c <- 4 m-panels x 8 n
    const int m0  = (swz >> 3) * 256;
    const int n0  = (swz & 7) * 128;

    const int srow  = t >> 3;
    const int sslot = ((t & 7) ^ (srow & 7)) * 8;
    const unsigned short* srcA1 = A1 + (size_t)(m0 + srow) * K_ + sslot;
    const unsigned short* srcA2 = A2 + (size_t)(m0 + srow) * K_ + sslot;
    const unsigned short* srcB  = W0 + (size_t)(n0 + srow) * K_ + sslot;
    char* dstA = lds + w * 1024;
    char* dstB = lds + 65536 + w * 1024;

    auto stageA = [&](int tt, int h) {   // A half h = rows [h*128, h*128+128)
        const unsigned short* base = (MODE == 2 && tt >= 8) ? srcA2 : srcA1;
        const unsigned short* s = base + (size_t)(h * 128) * K_ + tt * 64;
        char* d = dstA + (tt & 1) * 32768 + h * 16384;
        #pragma unroll
        for (int j = 0; j < 2; ++j)
            __builtin_amdgcn_global_load_lds(
                (const AS1 void*)(s + (size_t)j * 64 * K_),
                (AS3 void*)(d + j * 8192), 16, 0, 0);
    };
    auto stageB = [&](int tt, int h) {   // B half h = rows [h*64, h*64+64)
        const unsigned short* s = srcB + (size_t)(h * 64) * K_ + tt * 64;
        char* d = dstB + (tt & 1) * 16384 + h * 8192;
        __builtin_amdgcn_global_load_lds((const AS1 void*)s, (AS3 void*)d, 16, 0, 0);
    };

    const int fr = l & 15, kq = l >> 4;
    const int wm = w >> 1, wn = w & 1;                 // waves 4 x 2
    const int fx = (kq ^ (fr & 7)) << 4;
    const char* rdA0 = lds + (wm * 32 + fr) * 128 + fx;
    const char* rdA1 = lds + (wm * 32 + fr) * 128 + (fx ^ 64);
    const char* rdB0 = lds + 65536 + (wn * 32 + fr) * 128 + fx;
    const char* rdB1 = lds + 65536 + (wn * 32 + fr) * 128 + (fx ^ 64);

    bf16x8 af[2][2], bfr[2][2][2];
    f32x4 acc[4][4];
    #pragma unroll
    for (int i = 0; i < 4; ++i)
        #pragma unroll
        for (int jn = 0; jn < 4; ++jn) acc[i][jn] = (f32x4)0.0f;

    auto readA = [&](int half, int par) {
        #pragma unroll
        for (int mi = 0; mi < 2; ++mi) {
            af[mi][0] = *(const bf16x8*)(rdA0 + par * 32768 + half * 16384 + mi * 2048);
            af[mi][1] = *(const bf16x8*)(rdA1 + par * 32768 + half * 16384 + mi * 2048);
        }
    };
    auto readBall = [&](int par) {
        #pragma unroll
        for (int bh = 0; bh < 2; ++bh)
            #pragma unroll
            for (int ni = 0; ni < 2; ++ni) {
                bfr[bh][ni][0] = *(const bf16x8*)(rdB0 + par * 16384 + bh * 8192 + ni * 2048);
                bfr[bh][ni][1] = *(const bf16x8*)(rdB1 + par * 16384 + bh * 8192 + ni * 2048);
            }
    };
    auto quad16 = [&](int ah) {
        __builtin_amdgcn_s_setprio(1);
        #pragma unroll
        for (int bh = 0; bh < 2; ++bh)
            #pragma unroll
            for (int mi = 0; mi < 2; ++mi)
                #pragma unroll
                for (int ni = 0; ni < 2; ++ni)
                    #pragma unroll
                    for (int ks = 0; ks < 2; ++ks)
                        acc[ah * 2 + mi][bh * 2 + ni] =
                            __builtin_amdgcn_mfma_f32_16x16x32_bf16(
                                af[mi][ks], bfr[bh][ni][ks],
                                acc[ah * 2 + mi][bh * 2 + ni], 0, 0, 0);
        __builtin_amdgcn_s_setprio(0);
    };

    // prologue: t0 full (Alo,Ahi,B=6) + t1 partial (Alo,B=4); drain t0
    stageA(0, 0); stageA(0, 1); stageB(0, 0); stageB(0, 1);
    stageA(1, 0); stageB(1, 0); stageB(1, 1);
    vwait4(); barrier_();

    for (int j = 0; j < NITER; ++j) {
        const int tE = (2 * j + 2 < NT) ? 2 * j + 2 : 0;   // clamped redundant
        const int tO = (2 * j + 3 < NT) ? 2 * j + 3 : 0;
        readA(0, 0); readBall(0); stageA(2 * j + 1, 1);
        quad16(0); barrier_();
        readA(1, 0); stageA(tE, 0); stageB(tE, 0); stageB(tE, 1);
        quad16(1); vwait4(); barrier_();
        readA(0, 1); readBall(1); stageA(tE, 1);
        quad16(0); barrier_();
        readA(1, 1); stageA(tO, 0); stageB(tO, 0); stageB(tO, 1);
        quad16(1); vwait4(); barrier_();
    }
    asm volatile("s_waitcnt vmcnt(0)" ::: "memory");

    // epilogue: C/D col = lane&15, row = (lane>>4)*4 + jj
    const int rs4 = kq * 4;
    const int nB0 = n0 + wn * 32;
    const int mB0 = m0 + wm * 32;
    #pragma unroll
    for (int ah = 0; ah < 2; ++ah)
        #pragma unroll
        for (int mi = 0; mi < 2; ++mi)
            #pragma unroll
            for (int bh = 0; bh < 2; ++bh)
                #pragma unroll
                for (int ni = 0; ni < 2; ++ni) {
                    const int n = nB0 + bh * 64 + ni * 16 + fr;
                    const float bv = bias0[n];
                    #pragma unroll
                    for (int jj = 0; jj < 4; ++jj) {
                        const int m = mB0 + ah * 128 + mi * 16 + rs4 + jj;
                        const size_t ix = (size_t)m * H_ + n;
                        const float z = acc[ah * 2 + mi][bh * 2 + ni][jj] + bv;
                        if (MODE == 0) {
                            const float sp = (z > 15.f) ? z : __logf(1.0f + __expf(z));
                            itau_out[ix] = f2bf(__fdividef(1.0f, sp + 1e-6f));
                        } else if (MODE == 1) {
                            const float r = __fdividef(1.0f, 1.0f + __expf(-z));
                            gate_out[(size_t)m * K_ + 512 + n] = f2bf(r * hidden[ix]);
                        } else {
                            const float e2 = __expf(2.0f * z);
                            const float th = __fdividef(e2 - 1.0f, e2 + 1.0f);
                            const float h = hidden[ix];
                            const float it = bf2f(itau_in[ix]);
                            outF[ix] = h + (th - h) * it;
                        }
                    }
                }
}

extern "C" void kernel_launch(void* const* d_in, const int* in_sizes, int n_in,
                              void* d_out, int out_size, void* d_ws, size_t ws_size,
                              hipStream_t stream) {
    (void)in_sizes; (void)n_in; (void)out_size; (void)ws_size;

    const float* x     = (const float*)d_in[0];
    const float* hid   = (const float*)d_in[1];
    const float* W_tau = (const float*)d_in[2];
    const float* b_tau = (const float*)d_in[3];
    const float* W_r   = (const float*)d_in[4];
    const float* b_r   = (const float*)d_in[5];
    const float* W_h   = (const float*)d_in[6];
    const float* b_h   = (const float*)d_in[7];

    // workspace (~76.5 MB)
    unsigned short* cmb1 = (unsigned short*)d_ws;          // [8192][1536] = [x|hidden]
    unsigned short* cmb2 = cmb1 + (size_t)B_ * K_;         // [8192][1536] (gated in cols 512+)
    unsigned short* wtb  = cmb2 + (size_t)B_ * K_;         // [1024][1536]
    unsigned short* wrb  = wtb  + (size_t)H_ * K_;         // [1024][1536]
    unsigned short* whb  = wrb  + (size_t)H_ * K_;         // [1024][1536]
    unsigned short* itau = whb  + (size_t)H_ * K_;         // [8192][1024] bf16

    hipFuncSetAttribute(reinterpret_cast<const void*>(&gemm4<0>),
                        hipFuncAttributeMaxDynamicSharedMemorySize, 98304);
    hipFuncSetAttribute(reinterpret_cast<const void*>(&gemm4<1>),
                        hipFuncAttributeMaxDynamicSharedMemorySize, 98304);
    hipFuncSetAttribute(reinterpret_cast<const void*>(&gemm4<2>),
                        hipFuncAttributeMaxDynamicSharedMemorySize, 98304);

    const int th = 256;
    constexpr int NPREP = B_ * I_ / 8 + B_ * H_ / 8 + 3 * H_ * K_ / 8; // 2162688
    prep<<<NPREP / th, th, 0, stream>>>(x, hid, W_tau, W_r, W_h,
                                        cmb1, wtb, wrb, whb);

    dim3 g(8, 32);   // 256 blocks, 1/CU
    gemm4<0><<<g, 512, 98304, stream>>>(cmb1, cmb1, wtb, b_tau, nullptr, nullptr,
                                        nullptr, itau, nullptr);
    gemm4<1><<<g, 512, 98304, stream>>>(cmb1, cmb1, wrb, b_r, hid, nullptr,
                                        nullptr, nullptr, cmb2);
    gemm4<2><<<g, 512, 98304, stream>>>(cmb1, cmb2, whb, b_h, hid, itau,
                                        (float*)d_out, nullptr, nullptr);
}

// Round 15
// 105.993 us; speedup vs baseline: 2.0642x; 1.0648x over previous
//
#include <hip/hip_runtime.h>
#include <hip/hip_bf16.h>

typedef __attribute__((ext_vector_type(8))) unsigned short u16x8;
typedef __attribute__((ext_vector_type(8))) __bf16        bf16x8;
typedef __attribute__((ext_vector_type(4))) float         f32x4;

static constexpr int B_ = 8192;
static constexpr int I_ = 512;
static constexpr int H_ = 1024;
static constexpr int K_ = 1536;   // I_ + H_
static constexpr int NT    = K_ / 64;   // 24 K-tiles of BK=64
static constexpr int NITER = NT / 2;    // 12 iterations (2 tiles each)

#define AS1 __attribute__((address_space(1)))
#define AS3 __attribute__((address_space(3)))

__device__ __forceinline__ unsigned short f2bf(float f) {
    unsigned int u = __float_as_uint(f);
    u += 0x7FFF + ((u >> 16) & 1);          // RNE
    return (unsigned short)(u >> 16);
}
__device__ __forceinline__ float bf2f(unsigned short u) {
    return __uint_as_float(((unsigned int)u) << 16);
}

__device__ __forceinline__ void memfence() { asm volatile("" ::: "memory"); }
__device__ __forceinline__ void barrier_() {
    memfence(); __builtin_amdgcn_s_barrier(); memfence();
}
__device__ __forceinline__ void vwait6() {
    asm volatile("s_waitcnt vmcnt(6)" ::: "memory");
    __builtin_amdgcn_sched_barrier(0);
}
__device__ __forceinline__ void vwait0() {
    asm volatile("s_waitcnt vmcnt(0)" ::: "memory");
    __builtin_amdgcn_sched_barrier(0);
}

__device__ __forceinline__ u16x8 cvt8(const float4* s) {
    float4 a = s[0], b = s[1];
    u16x8 o;
    o[0] = f2bf(a.x); o[1] = f2bf(a.y); o[2] = f2bf(a.z); o[3] = f2bf(a.w);
    o[4] = f2bf(b.x); o[5] = f2bf(b.y); o[6] = f2bf(b.z); o[7] = f2bf(b.w);
    return o;
}

// ---- one-launch input prep: [x|hid]->cmb1 bf16, 3x W -> bf16 ---------------
__global__ void prep(const float* __restrict__ x, const float* __restrict__ hid,
                     const float* __restrict__ wt, const float* __restrict__ wr,
                     const float* __restrict__ wh,
                     unsigned short* __restrict__ cmb1,
                     unsigned short* __restrict__ wtb,
                     unsigned short* __restrict__ wrb,
                     unsigned short* __restrict__ whb) {
    constexpr int NX8 = B_ * I_ / 8;    // 524288
    constexpr int NH8 = B_ * H_ / 8;    // 1048576
    constexpr int NW8 = H_ * K_ / 8;    // 196608
    int i = blockIdx.x * blockDim.x + threadIdx.x;
    if (i < NX8) {
        int row = i >> 6, c8 = i & 63;
        u16x8 o = cvt8((const float4*)x + (size_t)i * 2);
        *(u16x8*)(cmb1 + (size_t)row * K_ + c8 * 8) = o;
    } else if (i < NX8 + NH8) {
        int j = i - NX8;
        int row = j >> 7, c8 = j & 127;
        u16x8 o = cvt8((const float4*)hid + (size_t)j * 2);
        *(u16x8*)(cmb1 + (size_t)row * K_ + 512 + c8 * 8) = o;
    } else {
        int k = i - (NX8 + NH8);
        const float* src; unsigned short* dst;
        if (k < NW8)          { src = wt; dst = wtb; }
        else if (k < 2 * NW8) { src = wr; dst = wrb; k -= NW8; }
        else                  { src = wh; dst = whb; k -= 2 * NW8; }
        u16x8 o = cvt8((const float4*)src + (size_t)k * 2);
        *(u16x8*)(dst + (size_t)k * 8) = o;
    }
}

// ===========================================================================
// gemm_tr: R9-verbatim FUSED tau+r. BM=256, BN=128, waves 4x2, BK=64,
// 2 tiles/iter, 32-MFMA phases (A-full in regs, one W's B at a time).
// LDS 128 KiB. vmcnt(6) at P2/P4. Proven race-free (R9, passed, 105.9 best).
//   wi=0: itau_out = bf16(1/(softplus(z)+eps))
//   wi=1: gate_out[m*K_+512+n] = bf16(sigmoid(z)*hidden_f32)
// ===========================================================================
__global__ __launch_bounds__(512, 1)
void gemm_tr(const unsigned short* __restrict__ A,
             const unsigned short* __restrict__ W0,
             const unsigned short* __restrict__ W1,
             const float* __restrict__ b0,
             const float* __restrict__ b1,
             const float* __restrict__ hidden,
             unsigned short* __restrict__ itau_out,
             unsigned short* __restrict__ gate_out)
{
    extern __shared__ __align__(16) char lds[];

    const int t = threadIdx.x;
    const int w = t >> 6, l = t & 63;
    const int wg  = blockIdx.y * 8 + blockIdx.x;
    const int swz = (wg & 7) * 32 + (wg >> 3);   // XCD c <- 4 m-panels x 8 n
    const int m0  = (swz >> 3) * 256;
    const int n0  = (swz & 7) * 128;

    const int srow  = t >> 3;
    const int sslot = ((t & 7) ^ (srow & 7)) * 8;
    const unsigned short* srcA  = A  + (size_t)(m0 + srow) * K_ + sslot;
    const unsigned short* srcB0 = W0 + (size_t)(n0 + srow) * K_ + sslot;
    const unsigned short* srcB1 = W1 + (size_t)(n0 + srow) * K_ + sslot;
    char* dstA = lds + w * 1024;
    char* dstB = lds + 65536 + w * 1024;

    auto stageA = [&](int tt) {          // full A tile: 4 loads
        const unsigned short* s = srcA + tt * 64;
        char* d = dstA + (tt & 1) * 32768;
        #pragma unroll
        for (int q = 0; q < 4; ++q)
            __builtin_amdgcn_global_load_lds(
                (const AS1 void*)(s + (size_t)q * 64 * K_),
                (AS3 void*)(d + q * 8192), 16, 0, 0);
    };
    auto stageB = [&](int tt, int wi) {  // one W tile: 2 loads
        const unsigned short* s = (wi ? srcB1 : srcB0) + tt * 64;
        char* d = dstB + (tt & 1) * 32768 + wi * 16384;
        #pragma unroll
        for (int h = 0; h < 2; ++h)
            __builtin_amdgcn_global_load_lds(
                (const AS1 void*)(s + (size_t)(h * 64) * K_),
                (AS3 void*)(d + h * 8192), 16, 0, 0);
    };

    const int fr = l & 15, kq = l >> 4;
    const int wm = w >> 1, wn = w & 1;                 // waves 4 x 2
    const int fx = (kq ^ (fr & 7)) << 4;
    const char* rdA0 = lds + (wm * 32 + fr) * 128 + fx;
    const char* rdA1 = lds + (wm * 32 + fr) * 128 + (fx ^ 64);
    const char* rdB0 = lds + 65536 + (wn * 32 + fr) * 128 + fx;
    const char* rdB1 = lds + 65536 + (wn * 32 + fr) * 128 + (fx ^ 64);

    bf16x8 af[4][2], bfr[2][2][2];       // af: full A tile; bfr: one W
    f32x4 acc[2][4][4];
    #pragma unroll
    for (int wi = 0; wi < 2; ++wi)
        #pragma unroll
        for (int i = 0; i < 4; ++i)
            #pragma unroll
            for (int jn = 0; jn < 4; ++jn) acc[wi][i][jn] = (f32x4)0.0f;

    auto readAfull = [&](int par) {      // 8 x b128: mf = ah*2+mi
        #pragma unroll
        for (int mf = 0; mf < 4; ++mf) {
            const int off = par * 32768 + (mf >> 1) * 16384 + (mf & 1) * 2048;
            af[mf][0] = *(const bf16x8*)(rdA0 + off);
            af[mf][1] = *(const bf16x8*)(rdA1 + off);
        }
    };
    auto readB = [&](int wi, int par) {  // 8 x b128: one W, full tile
        #pragma unroll
        for (int bh = 0; bh < 2; ++bh)
            #pragma unroll
            for (int ni = 0; ni < 2; ++ni) {
                const int off = par * 32768 + wi * 16384 + bh * 8192 + ni * 2048;
                bfr[bh][ni][0] = *(const bf16x8*)(rdB0 + off);
                bfr[bh][ni][1] = *(const bf16x8*)(rdB1 + off);
            }
    };
    auto mfma32 = [&](int wi) {          // 32 MFMA: all m-frags x held W
        __builtin_amdgcn_s_setprio(1);
        #pragma unroll
        for (int mf = 0; mf < 4; ++mf)
            #pragma unroll
            for (int bh = 0; bh < 2; ++bh)
                #pragma unroll
                for (int ni = 0; ni < 2; ++ni)
                    #pragma unroll
                    for (int ks = 0; ks < 2; ++ks)
                        acc[wi][mf][bh * 2 + ni] =
                            __builtin_amdgcn_mfma_f32_16x16x32_bf16(
                                af[mf][ks], bfr[bh][ni][ks],
                                acc[wi][mf][bh * 2 + ni], 0, 0, 0);
        __builtin_amdgcn_s_setprio(0);
    };

    // prologue: t0 full (A4+BW0 2+BW1 2 = 8) + t1 partial (A4+BW0 2 = 6)
    stageA(0); stageB(0, 0); stageB(0, 1);
    stageA(1); stageB(1, 0);
    vwait6(); barrier_();

    for (int j = 0; j < NITER; ++j) {
        const int tE = (2 * j + 2 < NT) ? 2 * j + 2 : 0;   // clamped redundant
        const int tO = (2 * j + 3 < NT) ? 2 * j + 3 : 0;
        // P1: A(b0)+BW0(b0); stage BW1 of odd tile
        readAfull(0); readB(0, 0); stageB(2 * j + 1, 1);
        mfma32(0); barrier_();
        // P2: BW1(b0); stage even-tile A + BW0
        readB(1, 0); stageA(tE); stageB(tE, 0);
        mfma32(1); vwait6(); barrier_();
        // P3: A(b1)+BW0(b1); stage even-tile BW1
        readAfull(1); readB(0, 1); stageB(tE, 1);
        mfma32(0); barrier_();
        // P4: BW1(b1); stage odd-tile A + BW0
        readB(1, 1); stageA(tO); stageB(tO, 0);
        mfma32(1); vwait6(); barrier_();
    }
    vwait0();

    // epilogue: C/D col = lane&15, row = (lane>>4)*4 + jj
    const int rs4 = kq * 4;
    const int nB0 = n0 + wn * 32;
    #pragma unroll
    for (int wi = 0; wi < 2; ++wi)
        #pragma unroll
        for (int mf = 0; mf < 4; ++mf)
            #pragma unroll
            for (int bh = 0; bh < 2; ++bh)
                #pragma unroll
                for (int ni = 0; ni < 2; ++ni) {
                    const int n = nB0 + bh * 64 + ni * 16 + fr;
                    const float bv = (wi ? b1 : b0)[n];
                    #pragma unroll
                    for (int jj = 0; jj < 4; ++jj) {
                        const int m = m0 + (mf >> 1) * 128 + wm * 32 + (mf & 1) * 16 + rs4 + jj;
                        const size_t ix = (size_t)m * H_ + n;
                        const float z = acc[wi][mf][bh * 2 + ni][jj] + bv;
                        if (wi == 0) {
                            const float sp = (z > 15.f) ? z : __logf(1.0f + __expf(z));
                            itau_out[ix] = f2bf(__fdividef(1.0f, sp + 1e-6f));
                        } else {
                            const float r = __fdividef(1.0f, 1.0f + __expf(-z));
                            gate_out[(size_t)m * K_ + 512 + n] = f2bf(r * hidden[ix]);
                        }
                    }
                }
}

// ===========================================================================
// gemm_h: R11-verbatim TLP kernel, mode-2 only. BM=128, BN=128, 256 thr
// (4 waves 2x2), BK=64, LDS 64 KiB -> 2 blocks/CU (co-resident block covers
// the epilogue burst). Per K-tile: {stage t+1 first; ds_read t; 32 MFMA;
// vmcnt(0); barrier}. A k<512 from cmb1, k>=512 from cmb2 (gated).
//   outF = h + (tanh(z)-h)*itau   (h f32, itau bf16)
// ===========================================================================
__global__ __launch_bounds__(256, 2)
void gemm_h(const unsigned short* __restrict__ A1,
            const unsigned short* __restrict__ A2,
            const unsigned short* __restrict__ W,
            const float* __restrict__ bias,
            const float* __restrict__ hidden,
            const unsigned short* __restrict__ itau_in,
            float* __restrict__ outF)
{
    extern __shared__ __align__(16) char lds[];

    const int t = threadIdx.x;
    const int w = t >> 6, l = t & 63;
    const int wg  = blockIdx.y * 8 + blockIdx.x;      // 0..511
    const int swz = (wg & 7) * 64 + (wg >> 3);        // bijective XCD remap
    const int m0  = (swz >> 3) * 128;
    const int n0  = (swz & 7) * 128;

    const int srow  = t >> 3;                          // 0..31
    const int sslot = ((t & 7) ^ (srow & 7)) * 8;      // swizzled 16B slot
    const unsigned short* srcA1 = A1 + (size_t)(m0 + srow) * K_ + sslot;
    const unsigned short* srcA2 = A2 + (size_t)(m0 + srow) * K_ + sslot;
    const unsigned short* srcB  = W  + (size_t)(n0 + srow) * K_ + sslot;

    auto stageTile = [&](int bi, int ts) {
        const unsigned short* sA = (ts >= 8 ? srcA2 : srcA1) + ts * 64;
        char* dA = lds + bi * 16384 + w * 1024;
        #pragma unroll
        for (int q = 0; q < 4; ++q)                    // rows q*32 + srow
            __builtin_amdgcn_global_load_lds(
                (const AS1 void*)(sA + (size_t)q * 32 * K_),
                (AS3 void*)(dA + q * 4096), 16, 0, 0);
        const unsigned short* sB = srcB + ts * 64;
        char* dB = lds + 32768 + bi * 16384 + w * 1024;
        #pragma unroll
        for (int q = 0; q < 4; ++q)
            __builtin_amdgcn_global_load_lds(
                (const AS1 void*)(sB + (size_t)q * 32 * K_),
                (AS3 void*)(dB + q * 4096), 16, 0, 0);
    };

    const int fr = l & 15, kq = l >> 4;
    const int wm = w >> 1, wn = w & 1;                 // waves 2 x 2
    const int fx = (kq ^ (fr & 7)) << 4;
    const char* rdA0 = lds + (wm * 64 + fr) * 128 + fx;
    const char* rdA1 = lds + (wm * 64 + fr) * 128 + (fx ^ 64);
    const char* rdB0 = lds + 32768 + (wn * 64 + fr) * 128 + fx;
    const char* rdB1 = lds + 32768 + (wn * 64 + fr) * 128 + (fx ^ 64);

    bf16x8 af[4][2], bfr[4][2];
    f32x4 acc[4][4];
    #pragma unroll
    for (int i = 0; i < 4; ++i)
        #pragma unroll
        for (int jn = 0; jn < 4; ++jn) acc[i][jn] = (f32x4)0.0f;

    auto readFrags = [&](int bi) {
        #pragma unroll
        for (int mf = 0; mf < 4; ++mf) {
            af[mf][0] = *(const bf16x8*)(rdA0 + bi * 16384 + mf * 2048);
            af[mf][1] = *(const bf16x8*)(rdA1 + bi * 16384 + mf * 2048);
        }
        #pragma unroll
        for (int nf = 0; nf < 4; ++nf) {
            bfr[nf][0] = *(const bf16x8*)(rdB0 + bi * 16384 + nf * 2048);
            bfr[nf][1] = *(const bf16x8*)(rdB1 + bi * 16384 + nf * 2048);
        }
    };
    auto mfma32 = [&]() {
        __builtin_amdgcn_s_setprio(1);
        #pragma unroll
        for (int mf = 0; mf < 4; ++mf)
            #pragma unroll
            for (int nf = 0; nf < 4; ++nf)
                #pragma unroll
                for (int ks = 0; ks < 2; ++ks)
                    acc[mf][nf] = __builtin_amdgcn_mfma_f32_16x16x32_bf16(
                        af[mf][ks], bfr[nf][ks], acc[mf][nf], 0, 0, 0);
        __builtin_amdgcn_s_setprio(0);
    };

    // prologue: stage tile 0 into buf0, drain
    stageTile(0, 0);
    vwait0(); barrier_();

    for (int ts = 0; ts < NT; ++ts) {
        const int bi = ts & 1;
        stageTile(bi ^ 1, (ts + 1 < NT) ? ts + 1 : 0);  // issue first (clamped)
        readFrags(bi);
        mfma32();
        vwait0(); barrier_();
    }

    // epilogue: C/D col = lane&15, row = (lane>>4)*4 + jj
    const int rs4 = kq * 4;
    #pragma unroll
    for (int mf = 0; mf < 4; ++mf)
        #pragma unroll
        for (int nf = 0; nf < 4; ++nf) {
            const int n = n0 + wn * 64 + nf * 16 + fr;
            const float bv = bias[n];
            #pragma unroll
            for (int jj = 0; jj < 4; ++jj) {
                const int m = m0 + wm * 64 + mf * 16 + rs4 + jj;
                const size_t ix = (size_t)m * H_ + n;
                const float z = acc[mf][nf][jj] + bv;
                const float e2 = __expf(2.0f * z);
                const float th = __fdividef(e2 - 1.0f, e2 + 1.0f);
                const float h = hidden[ix];
                const float it = bf2f(itau_in[ix]);
                outF[ix] = h + (th - h) * it;
            }
        }
}

extern "C" void kernel_launch(void* const* d_in, const int* in_sizes, int n_in,
                              void* d_out, int out_size, void* d_ws, size_t ws_size,
                              hipStream_t stream) {
    (void)in_sizes; (void)n_in; (void)out_size; (void)ws_size;

    const float* x     = (const float*)d_in[0];
    const float* hid   = (const float*)d_in[1];
    const float* W_tau = (const float*)d_in[2];
    const float* b_tau = (const float*)d_in[3];
    const float* W_r   = (const float*)d_in[4];
    const float* b_r   = (const float*)d_in[5];
    const float* W_h   = (const float*)d_in[6];
    const float* b_h   = (const float*)d_in[7];

    // workspace (~76.5 MB)
    unsigned short* cmb1 = (unsigned short*)d_ws;          // [8192][1536] = [x|hidden]
    unsigned short* cmb2 = cmb1 + (size_t)B_ * K_;         // [8192][1536] (gated in cols 512+)
    unsigned short* wtb  = cmb2 + (size_t)B_ * K_;         // [1024][1536]
    unsigned short* wrb  = wtb  + (size_t)H_ * K_;         // [1024][1536]
    unsigned short* whb  = wrb  + (size_t)H_ * K_;         // [1024][1536]
    unsigned short* itau = whb  + (size_t)H_ * K_;         // [8192][1024] bf16

    hipFuncSetAttribute(reinterpret_cast<const void*>(&gemm_tr),
                        hipFuncAttributeMaxDynamicSharedMemorySize, 131072);
    hipFuncSetAttribute(reinterpret_cast<const void*>(&gemm_h),
                        hipFuncAttributeMaxDynamicSharedMemorySize, 65536);

    const int th = 256;
    constexpr int NPREP = B_ * I_ / 8 + B_ * H_ / 8 + 3 * H_ * K_ / 8; // 2162688
    prep<<<NPREP / th, th, 0, stream>>>(x, hid, W_tau, W_r, W_h,
                                        cmb1, wtb, wrb, whb);

    dim3 g0(8, 32);   // 256 blocks, 1/CU
    gemm_tr<<<g0, 512, 131072, stream>>>(cmb1, wtb, wrb, b_tau, b_r, hid,
                                         itau, cmb2);
    dim3 g1(8, 64);   // 512 blocks, 2/CU
    gemm_h<<<g1, 256, 65536, stream>>>(cmb1, cmb2, whb, b_h, hid, itau,
                                       (float*)d_out);
}